// Round 15
// baseline (214.771 us; speedup 1.0000x reference)
//
#include <hip/hip_runtime.h>
#include <stdint.h>

#define N_NODES 8192
#define IN_FEAT 512
#define OUT_FEAT 256
#define LOG2E 1.4426950408889634f

typedef __bf16 b16x8 __attribute__((ext_vector_type(8)));
typedef unsigned short u16x8v __attribute__((ext_vector_type(8)));
typedef float f32x4 __attribute__((ext_vector_type(4)));

static __device__ __forceinline__ unsigned short f2bf(float f) {
    union { float f; uint32_t u; } v; v.f = f;
    uint32_t r = v.u + 0x7FFFu + ((v.u >> 16) & 1u);
    return (unsigned short)(r >> 16);
}

// K0: Wt[c][k] = bf16(W[k][c])  (256 x 512)
__global__ __launch_bounds__(256) void k0_transpose_w(const float* __restrict__ W,
                                                      unsigned short* __restrict__ Wt) {
    int tid = blockIdx.x * 256 + threadIdx.x;
    int c = tid & (OUT_FEAT - 1);
    int k = tid >> 8;
    Wt[(size_t)c * IN_FEAT + k] = f2bf(W[(size_t)k * OUT_FEAT + c]);
}

// K1: h = X @ W via bf16 MFMA. Writes hTf in MFMA-B-fragment order.
__global__ __launch_bounds__(256) void k1_hgemm(const float* __restrict__ input,
                                                const unsigned short* __restrict__ Wt,
                                                const float* __restrict__ a_vec,
                                                unsigned short* __restrict__ hTf,
                                                float* __restrict__ s1_raw,
                                                float* __restrict__ s2_raw) {
    int tid = threadIdx.x;
    int lane = tid & 63;
    int c = lane & 15, g = lane >> 4;
    int r0 = blockIdx.x * 64 + (tid >> 6) * 16;
    f32x4 acc[16];
#pragma unroll
    for (int t = 0; t < 16; ++t) acc[t] = (f32x4){0.f, 0.f, 0.f, 0.f};
    const float* arow = input + (size_t)(r0 + c) * IN_FEAT;
#pragma unroll 1
    for (int kk = 0; kk < IN_FEAT / 32; ++kk) {
        int kb = kk * 32 + 8 * g;
        float4 x0 = *(const float4*)(arow + kb);
        float4 x1 = *(const float4*)(arow + kb + 4);
        u16x8v au;
        au[0] = f2bf(x0.x); au[1] = f2bf(x0.y); au[2] = f2bf(x0.z); au[3] = f2bf(x0.w);
        au[4] = f2bf(x1.x); au[5] = f2bf(x1.y); au[6] = f2bf(x1.z); au[7] = f2bf(x1.w);
        b16x8 af = __builtin_bit_cast(b16x8, au);
#pragma unroll
        for (int t = 0; t < 16; ++t) {
            b16x8 bf = __builtin_bit_cast(b16x8,
                *(const u16x8v*)(Wt + (size_t)(16 * t + c) * IN_FEAT + kb));
            acc[t] = __builtin_amdgcn_mfma_f32_16x16x32_bf16(af, bf, acc[t], 0, 0, 0);
        }
    }
    float a1v[16], a2v[16];
#pragma unroll
    for (int t = 0; t < 16; ++t) {
        a1v[t] = a_vec[16 * t + c];
        a2v[t] = a_vec[OUT_FEAT + 16 * t + c];
    }
#pragma unroll
    for (int r = 0; r < 4; ++r) {
        float s1p = 0.f, s2p = 0.f;
#pragma unroll
        for (int t = 0; t < 16; ++t) { s1p += acc[t][r] * a1v[t]; s2p += acc[t][r] * a2v[t]; }
#pragma unroll
        for (int m = 1; m <= 8; m <<= 1) { s1p += __shfl_xor(s1p, m); s2p += __shfl_xor(s2p, m); }
        if (c == 0) {
            int row = r0 + 4 * g + r;
            s1_raw[row] = s1p;
            s2_raw[row] = s2p;
        }
    }
    int chunk = r0 >> 5;
    int lp = ((r0 & 16) >> 3) + (g >> 1);
    int e0 = 4 * (g & 1);
#pragma unroll
    for (int t = 0; t < 16; ++t) {
        ushort4 pk;
        pk.x = f2bf(acc[t][0]); pk.y = f2bf(acc[t][1]);
        pk.z = f2bf(acc[t][2]); pk.w = f2bf(acc[t][3]);
        *(ushort4*)(hTf + ((size_t)(chunk * 16 + t) * 64 + lp * 16 + c) * 8 + e0) = pk;
    }
}

// K2: factored-exp constants.
__global__ __launch_bounds__(256) void k2_prep(const float* __restrict__ s1_raw,
                                               const float* __restrict__ s2_raw,
                                               float* __restrict__ e12,
                                               float2* __restrict__ row2) {
    __shared__ float red[256];
    int tid = threadIdx.x;
    float m = -3.0e38f;
    for (int j = tid; j < N_NODES; j += 256) m = fmaxf(m, s2_raw[j]);
    red[tid] = m;
    __syncthreads();
    for (int s = 128; s > 0; s >>= 1) {
        if (tid < s) red[tid] = fmaxf(red[tid], red[tid + s]);
        __syncthreads();
    }
    float M2 = red[0];
    int i = blockIdx.x * 256 + tid;
    float s1 = s1_raw[i];
    float u = s1 + M2;
    float mi = fmaxf(u, 0.2f * u);                 // per-row upper bound on e
    row2[i] = make_float2(__builtin_amdgcn_exp2f((s1 - mi) * LOG2E),
                          __builtin_amdgcn_exp2f((0.2f * s1 - mi) * LOG2E));
    float s2 = s2_raw[i];
    e12[2 * i]     = __builtin_amdgcn_exp2f(s2 * LOG2E);
    e12[2 * i + 1] = __builtin_amdgcn_exp2f(0.2f * s2 * LOG2E);
}

// K3 v14: FUSED adj-read + flash-GAT partials, barrier-free, 4 waves/SIMD.
// Grid 1024 = 256 rowgroups (32 rows) x 4 jq. Block = 256 = 4 waves (rq x ch).
// Wave: 16 rows x 128 cols x 64 chunks; reads raw adj directly (2 int4/lane/
// chunk, per-element cmp+cndmask masking — no bitmask pass, k_pack deleted).
// Rowsum via extra MFMA against ones-B (replaces VALU adds + shuffles).
// adj HBM (512 MB with ch x2 duplication) overlaps L1/VALU/MFMA work.
__global__ __launch_bounds__(256, 4) void k3_flash(const int* __restrict__ adj,
                                                   const unsigned short* __restrict__ hTf,
                                                   const float* __restrict__ e12g,
                                                   const float2* __restrict__ row2,
                                                   float* __restrict__ pout,
                                                   float* __restrict__ rowpart) {
    __shared__ __align__(16) float le12[4096];               // 16 KB

    int tid = threadIdx.x;
    int w = tid >> 6, lane = tid & 63;
    int c = lane & 15, g = lane >> 4;
    int ch = w & 1, rq = w >> 1;
    int jq = blockIdx.x & 3;
    int rg = blockIdx.x >> 2;
    int rowbase = rg * 32 + rq * 16;

    // prologue: stage e12 quarter (16 floats/thread), one barrier
#pragma unroll
    for (int q = 0; q < 4; ++q) {
        *(float4*)&le12[tid * 16 + q * 4] =
            *(const float4*)(e12g + (size_t)jq * 4096 + tid * 16 + q * 4);
    }
    float2 rc0 = row2[rowbase + c];
    float E1r0 = rc0.x, E2r0 = rc0.y;
    __syncthreads();

    // raw adj base for this lane's row and j-octet
    const int* adjbase = adj + (size_t)(rowbase + c) * N_NODES + jq * 2048 + 8 * g;

    // ones B-frag for rowsum MFMA
    u16x8v ou;
#pragma unroll
    for (int e = 0; e < 8; ++e) ou[e] = 0x3F80;              // bf16 1.0
    b16x8 ones = __builtin_bit_cast(b16x8, ou);

    f32x4 acc0[8], accS;
#pragma unroll
    for (int t = 0; t < 8; ++t) acc0[t] = (f32x4){0, 0, 0, 0};
    accS = (f32x4){0, 0, 0, 0};

#pragma unroll 2
    for (int kk = 0; kk < 64; ++kk) {
        int jchunk = jq * 64 + kk;
        const unsigned short* tb = hTf + (size_t)(jchunk * 16 + ch * 8) * 512 + lane * 8;

        // issue adj loads (HBM, longest latency) then b-frags 0..3 (L2)
        int4 v0 = *(const int4*)(adjbase + kk * 32);
        int4 v1 = *(const int4*)(adjbase + kk * 32 + 4);
        b16x8 bfv[4];
#pragma unroll
        for (int t = 0; t < 4; ++t)
            bfv[t] = __builtin_bit_cast(b16x8, *(const u16x8v*)(tb + t * 512));

        // score for 16 rows x 8 js (factored exp; float2 product, per-elem mask)
        int av[8] = {v0.x, v0.y, v0.z, v0.w, v1.x, v1.y, v1.z, v1.w};
        b16x8 af0;
#pragma unroll
        for (int e = 0; e < 8; ++e) {
            float2 ep = *(const float2*)&le12[(kk * 32 + 8 * g + e) * 2];
            float px = E1r0 * ep.x;
            float py = E2r0 * ep.y;
            float q0 = fmaxf(px, py);
            float p0 = (av[e] != 0) ? q0 : 0.f;
            af0[e] = (__bf16)p0;
        }

        // rowsum MFMA + mfma 0..3
        accS = __builtin_amdgcn_mfma_f32_16x16x32_bf16(af0, ones, accS, 0, 0, 0);
#pragma unroll
        for (int t = 0; t < 4; ++t)
            acc0[t] = __builtin_amdgcn_mfma_f32_16x16x32_bf16(af0, bfv[t], acc0[t], 0, 0, 0);

        // b-frags 4..7, then mfma
        b16x8 bfw[4];
#pragma unroll
        for (int t = 0; t < 4; ++t)
            bfw[t] = __builtin_bit_cast(b16x8, *(const u16x8v*)(tb + (t + 4) * 512));
#pragma unroll
        for (int t = 0; t < 4; ++t)
            acc0[t + 4] = __builtin_amdgcn_mfma_f32_16x16x32_bf16(af0, bfw[t], acc0[t + 4], 0, 0, 0);
    }

    // rowsum: accS[r] holds sum_j p[row=4g+r][*] (all cols identical); ch=0, col c==0 writes
    if (ch == 0 && c == 0) {
#pragma unroll
        for (int r = 0; r < 4; ++r)
            rowpart[jq * N_NODES + rowbase + 4 * g + r] = accS[r];
    }

#pragma unroll
    for (int r = 0; r < 4; ++r) {
        int grow0 = rowbase + 4 * g + r;        // C layout: row=(lane>>4)*4+reg
#pragma unroll
        for (int t = 0; t < 8; ++t) {
            pout[((size_t)jq * N_NODES + grow0) * OUT_FEAT + ch * 128 + 16 * t + c] = acc0[t][r];
        }
    }
}

// K4: out = elu( (sum_q pout[q]) / (sum_q rowpart[q]) ).
__global__ __launch_bounds__(256) void k4_reduce(const float* __restrict__ pout,
                                                 const float* __restrict__ rowpart,
                                                 float* __restrict__ out) {
    int t = blockIdx.x * 256 + threadIdx.x;
    int row = t >> 8;
    float s = 0.f, l = 0.f;
#pragma unroll
    for (int q = 0; q < 4; ++q) {
        s += pout[(size_t)q * N_NODES * OUT_FEAT + t];
        l += rowpart[q * N_NODES + row];
    }
    float inv = (l > 0.f) ? 1.0f / l : 0.f;
    float x = s * inv;
    out[t] = (x > 0.f) ? x : (__builtin_amdgcn_exp2f(x * LOG2E) - 1.0f);
}

extern "C" void kernel_launch(void* const* d_in, const int* in_sizes, int n_in,
                              void* d_out, int out_size, void* d_ws, size_t ws_size,
                              hipStream_t stream) {
    const float* input = (const float*)d_in[0];
    const int* adj = (const int*)d_in[1];
    const float* W = (const float*)d_in[2];
    const float* a_vec = (const float*)d_in[3];
    float* out = (float*)d_out;

    char* ws = (char*)d_ws;
    unsigned short* Wt  = (unsigned short*)(ws);                 // 256 KB
    unsigned short* hTf = (unsigned short*)(ws + 262144);        // 4 MB
    float*  e12     = (float*)(ws + 4456448);                    // 64 KB
    float2* row2    = (float2*)(ws + 4521984);                   // 64 KB
    float*  s1_raw  = (float*)(ws + 4587520);                    // 32 KB
    float*  s2_raw  = (float*)(ws + 4620288);                    // 32 KB
    float*  rowpart = (float*)(ws + 13041664);                   // 128 KB
    float*  pout    = (float*)(ws + 13172736);                   // 32 MB

    hipLaunchKernelGGL(k0_transpose_w, dim3(512), dim3(256), 0, stream, W, Wt);
    hipLaunchKernelGGL(k1_hgemm, dim3(N_NODES / 64), dim3(256), 0, stream,
                       input, Wt, a_vec, hTf, s1_raw, s2_raw);
    hipLaunchKernelGGL(k2_prep, dim3(32), dim3(256), 0, stream, s1_raw, s2_raw, e12, row2);
    hipLaunchKernelGGL(k3_flash, dim3(1024), dim3(256), 0, stream,
                       adj, hTf, e12, row2, pout, rowpart);
    hipLaunchKernelGGL(k4_reduce, dim3(N_NODES * OUT_FEAT / 256), dim3(256), 0, stream,
                       pout, rowpart, out);
}

// Round 16
// 177.258 us; speedup vs baseline: 1.2116x; 1.2116x over previous
//
#include <hip/hip_runtime.h>
#include <stdint.h>

#define N_NODES 8192
#define IN_FEAT 512
#define OUT_FEAT 256
#define LOG2E 1.4426950408889634f

typedef __bf16 b16x8 __attribute__((ext_vector_type(8)));
typedef unsigned short u16x8v __attribute__((ext_vector_type(8)));
typedef float f32x4 __attribute__((ext_vector_type(4)));
typedef float f32x16 __attribute__((ext_vector_type(16)));

static __device__ __forceinline__ unsigned short f2bf(float f) {
    union { float f; uint32_t u; } v; v.f = f;
    uint32_t r = v.u + 0x7FFFu + ((v.u >> 16) & 1u);
    return (unsigned short)(r >> 16);
}

// K_pack: adj int32 [8192][8192] -> ROW-MAJOR bitmask (8 MB). Fully coalesced
// (measured ~45us @ 86% HBM — near-optimal for the compulsory 256 MB read).
__global__ __launch_bounds__(256) void k_pack(const int* __restrict__ adj,
                                              unsigned char* __restrict__ bitsR) {
    size_t t = (size_t)blockIdx.x * 256 + threadIdx.x;
    const int4* a4 = (const int4*)adj + t * 2;
    int4 x0 = a4[0];
    int4 x1 = a4[1];
    unsigned b = (unsigned)(x0.x != 0)
               | ((unsigned)(x0.y != 0) << 1)
               | ((unsigned)(x0.z != 0) << 2)
               | ((unsigned)(x0.w != 0) << 3)
               | ((unsigned)(x1.x != 0) << 4)
               | ((unsigned)(x1.y != 0) << 5)
               | ((unsigned)(x1.z != 0) << 6)
               | ((unsigned)(x1.w != 0) << 7);
    bitsR[t] = (unsigned char)b;
}

// K0: Wt[c][k] = bf16(W[k][c])  (256 x 512)
__global__ __launch_bounds__(256) void k0_transpose_w(const float* __restrict__ W,
                                                      unsigned short* __restrict__ Wt) {
    int tid = blockIdx.x * 256 + threadIdx.x;
    int c = tid & (OUT_FEAT - 1);
    int k = tid >> 8;
    Wt[(size_t)c * IN_FEAT + k] = f2bf(W[(size_t)k * OUT_FEAT + c]);
}

// K1: h = X @ W via bf16 MFMA (16x16x32 internally). Writes hTf32 in the
// B-fragment order of mfma_f32_32x32x16_bf16:
//   hTf32[((chunk16*8 + tile32)*64 + lane)*8 + e] = bf16(h[j][col])
//   where chunk16 = j>>4, tile32 = col>>5, lane = (col&31) | (((j>>3)&1)<<5),
//   e = j&7.
// k1's acc[t'][r] holds h[row=r0+4g+r][col=16t'+c] (16x16x32 C layout), so:
//   chunk16 = r0>>4 (const/wave), tile32 = t'>>1,
//   lane_t = 16*(t'&1) + c + 32*(g>>1), e0 = 4*(g&1) (4 consecutive e's = r).
__global__ __launch_bounds__(256) void k1_hgemm(const float* __restrict__ input,
                                                const unsigned short* __restrict__ Wt,
                                                const float* __restrict__ a_vec,
                                                unsigned short* __restrict__ hTf32,
                                                float* __restrict__ s1_raw,
                                                float* __restrict__ s2_raw) {
    int tid = threadIdx.x;
    int lane = tid & 63;
    int c = lane & 15, g = lane >> 4;
    int r0 = blockIdx.x * 64 + (tid >> 6) * 16;
    f32x4 acc[16];
#pragma unroll
    for (int t = 0; t < 16; ++t) acc[t] = (f32x4){0.f, 0.f, 0.f, 0.f};
    const float* arow = input + (size_t)(r0 + c) * IN_FEAT;
#pragma unroll 1
    for (int kk = 0; kk < IN_FEAT / 32; ++kk) {
        int kb = kk * 32 + 8 * g;
        float4 x0 = *(const float4*)(arow + kb);
        float4 x1 = *(const float4*)(arow + kb + 4);
        u16x8v au;
        au[0] = f2bf(x0.x); au[1] = f2bf(x0.y); au[2] = f2bf(x0.z); au[3] = f2bf(x0.w);
        au[4] = f2bf(x1.x); au[5] = f2bf(x1.y); au[6] = f2bf(x1.z); au[7] = f2bf(x1.w);
        b16x8 af = __builtin_bit_cast(b16x8, au);
#pragma unroll
        for (int t = 0; t < 16; ++t) {
            b16x8 bf = __builtin_bit_cast(b16x8,
                *(const u16x8v*)(Wt + (size_t)(16 * t + c) * IN_FEAT + kb));
            acc[t] = __builtin_amdgcn_mfma_f32_16x16x32_bf16(af, bf, acc[t], 0, 0, 0);
        }
    }
    float a1v[16], a2v[16];
#pragma unroll
    for (int t = 0; t < 16; ++t) {
        a1v[t] = a_vec[16 * t + c];
        a2v[t] = a_vec[OUT_FEAT + 16 * t + c];
    }
#pragma unroll
    for (int r = 0; r < 4; ++r) {
        float s1p = 0.f, s2p = 0.f;
#pragma unroll
        for (int t = 0; t < 16; ++t) { s1p += acc[t][r] * a1v[t]; s2p += acc[t][r] * a2v[t]; }
#pragma unroll
        for (int m = 1; m <= 8; m <<= 1) { s1p += __shfl_xor(s1p, m); s2p += __shfl_xor(s2p, m); }
        if (c == 0) {
            int row = r0 + 4 * g + r;
            s1_raw[row] = s1p;
            s2_raw[row] = s2p;
        }
    }
    // store in 32x32 B-frag order
    int chunk16 = r0 >> 4;
    int lane_base = c + 32 * (g >> 1);
    int e0 = 4 * (g & 1);
#pragma unroll
    for (int t = 0; t < 16; ++t) {
        ushort4 pk;
        pk.x = f2bf(acc[t][0]); pk.y = f2bf(acc[t][1]);
        pk.z = f2bf(acc[t][2]); pk.w = f2bf(acc[t][3]);
        int lane_t = 16 * (t & 1) + lane_base;
        *(ushort4*)(hTf32 + ((size_t)(chunk16 * 8 + (t >> 1)) * 64 + lane_t) * 8 + e0) = pk;
    }
}

// K2: factored-exp constants.
__global__ __launch_bounds__(256) void k2_prep(const float* __restrict__ s1_raw,
                                               const float* __restrict__ s2_raw,
                                               float* __restrict__ e12,
                                               float2* __restrict__ row2) {
    __shared__ float red[256];
    int tid = threadIdx.x;
    float m = -3.0e38f;
    for (int j = tid; j < N_NODES; j += 256) m = fmaxf(m, s2_raw[j]);
    red[tid] = m;
    __syncthreads();
    for (int s = 128; s > 0; s >>= 1) {
        if (tid < s) red[tid] = fmaxf(red[tid], red[tid + s]);
        __syncthreads();
    }
    float M2 = red[0];
    int i = blockIdx.x * 256 + tid;
    float s1 = s1_raw[i];
    float u = s1 + M2;
    float mi = fmaxf(u, 0.2f * u);                 // per-row upper bound on e
    row2[i] = make_float2(__builtin_amdgcn_exp2f((s1 - mi) * LOG2E),
                          __builtin_amdgcn_exp2f((0.2f * s1 - mi) * LOG2E));
    float s2 = s2_raw[i];
    e12[2 * i]     = __builtin_amdgcn_exp2f(s2 * LOG2E);
    e12[2 * i + 1] = __builtin_amdgcn_exp2f(0.2f * s2 * LOG2E);
}

// K3 v15: barrier-free flash-GAT partials using mfma_f32_32x32x16_bf16.
// Grid 1024 = 256 rowgroups (32 rows) x 4 jq. Block = 256 = 4 waves, wave cq
// owns cols 64cq..64cq+63 (2 col-tiles of 32). Wave = 32 rows x 64 cols,
// acc = 2 x f32x16 = 32 VGPRs -> ~85 regs total, register-safe at 4 waves/SIMD.
// Each wave reads DISTINCT b-frags (no rq duplication) -> per-CU L1 traffic
// halves vs R14. A-frag: p[row=lane&31][k=8*(lane>>5)+e]; score dup x4 across
// cq waves (~20us VALU, overlaps L1). e12 via 4x ds_read_b128 per chunk.
__global__ __launch_bounds__(256, 4) void k3_flash(const uint32_t* __restrict__ maskR,
                                                   const unsigned short* __restrict__ hTf32,
                                                   const float* __restrict__ e12g,
                                                   const float2* __restrict__ row2,
                                                   float* __restrict__ pout,
                                                   float* __restrict__ rowpart) {
    __shared__ __align__(16) float le12[4096];               // 16 KB

    int tid = threadIdx.x;
    int cq = tid >> 6, lane = tid & 63;
    int lr = lane & 31, lo = lane >> 5;
    int jq = blockIdx.x & 3;
    int rg = blockIdx.x >> 2;
    int rowbase = rg * 32;

    // prologue: stage e12 quarter (16 floats/thread), one barrier
#pragma unroll
    for (int q = 0; q < 4; ++q) {
        *(float4*)&le12[tid * 16 + q * 4] =
            *(const float4*)(e12g + (size_t)jq * 4096 + tid * 16 + q * 4);
    }
    float2 rc = row2[rowbase + lr];
    float E1r = rc.x, E2r = rc.y;
    __syncthreads();

    // mask pointer: row lr, quarter jq (64 dwords), int4-grouped (8 chunk16s per int4)
    const int4* m4 = (const int4*)(maskR + (size_t)(rowbase + lr) * 256 + jq * 64);

    f32x16 acc0 = {0}, acc1 = {0};
    float lacc = 0.f;

#pragma unroll 1
    for (int kc8 = 0; kc8 < 16; ++kc8) {
        int4 mq = m4[kc8];           // masks for 8 chunk16s (4 dwords x 32 js)
        uint32_t md[4] = {(uint32_t)mq.x, (uint32_t)mq.y, (uint32_t)mq.z, (uint32_t)mq.w};
#pragma unroll
        for (int sub = 0; sub < 8; ++sub) {
            int kc = kc8 * 8 + sub;                    // chunk16 index in quarter (0..127)
            int gchunk = jq * 128 + kc;                // global chunk16
            const unsigned short* tb =
                hTf32 + ((size_t)(gchunk * 8 + 2 * cq) * 64 + lane) * 8;

            // b-frags for this wave's 2 col-tiles (issued before score)
            b16x8 bf0 = __builtin_bit_cast(b16x8, *(const u16x8v*)(tb));
            b16x8 bf1 = __builtin_bit_cast(b16x8, *(const u16x8v*)(tb + 512));

            // e-factors: 8 js x (e1,e2) = 16 floats, 4x ds_read_b128
            float ev[16];
#pragma unroll
            for (int q = 0; q < 4; ++q)
                *(f32x4*)&ev[q * 4] = *(const f32x4*)&le12[(kc * 16 + 8 * lo) * 2 + q * 4];

            // score: row lr, js octet lo of this 16-j chunk
            uint32_t mb = (md[sub >> 1] >> (16 * (sub & 1) + 8 * lo)) & 0xFFu;
            b16x8 af;
#pragma unroll
            for (int e = 0; e < 8; ++e) {
                float q0 = fmaxf(E1r * ev[2 * e], E2r * ev[2 * e + 1]);
                float p = (mb & (1u << e)) ? q0 : 0.f;
                lacc += p;
                af[e] = (__bf16)p;
            }

            acc0 = __builtin_amdgcn_mfma_f32_32x32x16_bf16(af, bf0, acc0, 0, 0, 0);
            acc1 = __builtin_amdgcn_mfma_f32_32x32x16_bf16(af, bf1, acc1, 0, 0, 0);
        }
    }

    // row sums: lanes lr and lr+32 hold the two k-octets of row lr
    float ltot = lacc + __shfl_xor(lacc, 32);
    if (cq == 0 && lo == 0) rowpart[jq * N_NODES + rowbase + lr] = ltot;

    // C layout (32x32): col = lane&31, row = (reg&3) + 8*(reg>>2) + 4*(lane>>5)
#pragma unroll
    for (int reg = 0; reg < 16; ++reg) {
        int row = (reg & 3) + 8 * (reg >> 2) + 4 * lo;
        size_t base = ((size_t)jq * N_NODES + rowbase + row) * OUT_FEAT + cq * 64 + lr;
        pout[base] = acc0[reg];
        pout[base + 32] = acc1[reg];
    }
}

// K4: out = elu( (sum_q pout[q]) / (sum_q rowpart[q]) ).
__global__ __launch_bounds__(256) void k4_reduce(const float* __restrict__ pout,
                                                 const float* __restrict__ rowpart,
                                                 float* __restrict__ out) {
    int t = blockIdx.x * 256 + threadIdx.x;
    int row = t >> 8;
    float s = 0.f, l = 0.f;
#pragma unroll
    for (int q = 0; q < 4; ++q) {
        s += pout[(size_t)q * N_NODES * OUT_FEAT + t];
        l += rowpart[q * N_NODES + row];
    }
    float inv = (l > 0.f) ? 1.0f / l : 0.f;
    float x = s * inv;
    out[t] = (x > 0.f) ? x : (__builtin_amdgcn_exp2f(x * LOG2E) - 1.0f);
}

extern "C" void kernel_launch(void* const* d_in, const int* in_sizes, int n_in,
                              void* d_out, int out_size, void* d_ws, size_t ws_size,
                              hipStream_t stream) {
    const float* input = (const float*)d_in[0];
    const int* adj = (const int*)d_in[1];
    const float* W = (const float*)d_in[2];
    const float* a_vec = (const float*)d_in[3];
    float* out = (float*)d_out;

    char* ws = (char*)d_ws;
    unsigned short* Wt    = (unsigned short*)(ws);               // 256 KB
    unsigned short* hTf32 = (unsigned short*)(ws + 262144);      // 4 MB
    float*  e12     = (float*)(ws + 4456448);                    // 64 KB
    float2* row2    = (float2*)(ws + 4521984);                   // 64 KB
    float*  s1_raw  = (float*)(ws + 4587520);                    // 32 KB
    float*  s2_raw  = (float*)(ws + 4620288);                    // 32 KB
    unsigned char* bitsR = (unsigned char*)(ws + 4653056);       // 8 MB
    float*  rowpart = (float*)(ws + 13041664);                   // 128 KB
    float*  pout    = (float*)(ws + 13172736);                   // 32 MB

    hipLaunchKernelGGL(k_pack, dim3(32768), dim3(256), 0, stream, adj, bitsR);
    hipLaunchKernelGGL(k0_transpose_w, dim3(512), dim3(256), 0, stream, W, Wt);
    hipLaunchKernelGGL(k1_hgemm, dim3(N_NODES / 64), dim3(256), 0, stream,
                       input, Wt, a_vec, hTf32, s1_raw, s2_raw);
    hipLaunchKernelGGL(k2_prep, dim3(32), dim3(256), 0, stream, s1_raw, s2_raw, e12, row2);
    hipLaunchKernelGGL(k3_flash, dim3(1024), dim3(256), 0, stream,
                       (const uint32_t*)bitsR, hTf32, e12, row2, pout, rowpart);
    hipLaunchKernelGGL(k4_reduce, dim3(N_NODES * OUT_FEAT / 256), dim3(256), 0, stream,
                       pout, rowpart, out);
}

// Round 17
// 161.027 us; speedup vs baseline: 1.3338x; 1.1008x over previous
//
#include <hip/hip_runtime.h>
#include <stdint.h>

#define N_NODES 8192
#define IN_FEAT 512
#define OUT_FEAT 256
#define LOG2E 1.4426950408889634f

typedef __bf16 b16x8 __attribute__((ext_vector_type(8)));
typedef unsigned short u16x8v __attribute__((ext_vector_type(8)));
typedef float f32x4 __attribute__((ext_vector_type(4)));
typedef float f32x16 __attribute__((ext_vector_type(16)));

static __device__ __forceinline__ unsigned short f2bf(float f) {
    union { float f; uint32_t u; } v; v.f = f;
    uint32_t r = v.u + 0x7FFFu + ((v.u >> 16) & 1u);
    return (unsigned short)(r >> 16);
}

// K_pack: adj int32 [8192][8192] -> ROW-MAJOR bitmask (8 MB). Fully coalesced
// (measured ~45us @ 86% HBM — near-optimal for the compulsory 256 MB read).
__global__ __launch_bounds__(256) void k_pack(const int* __restrict__ adj,
                                              unsigned char* __restrict__ bitsR) {
    size_t t = (size_t)blockIdx.x * 256 + threadIdx.x;
    const int4* a4 = (const int4*)adj + t * 2;
    int4 x0 = a4[0];
    int4 x1 = a4[1];
    unsigned b = (unsigned)(x0.x != 0)
               | ((unsigned)(x0.y != 0) << 1)
               | ((unsigned)(x0.z != 0) << 2)
               | ((unsigned)(x0.w != 0) << 3)
               | ((unsigned)(x1.x != 0) << 4)
               | ((unsigned)(x1.y != 0) << 5)
               | ((unsigned)(x1.z != 0) << 6)
               | ((unsigned)(x1.w != 0) << 7);
    bitsR[t] = (unsigned char)b;
}

// K0: Wt[c][k] = bf16(W[k][c])  (256 x 512)
__global__ __launch_bounds__(256) void k0_transpose_w(const float* __restrict__ W,
                                                      unsigned short* __restrict__ Wt) {
    int tid = blockIdx.x * 256 + threadIdx.x;
    int c = tid & (OUT_FEAT - 1);
    int k = tid >> 8;
    Wt[(size_t)c * IN_FEAT + k] = f2bf(W[(size_t)k * OUT_FEAT + c]);
}

// K1: h = X @ W via bf16 MFMA (16x16x32 internally). Writes hTf32 in the
// B-fragment order of mfma_f32_32x32x16_bf16 (verified R16).
__global__ __launch_bounds__(256) void k1_hgemm(const float* __restrict__ input,
                                                const unsigned short* __restrict__ Wt,
                                                const float* __restrict__ a_vec,
                                                unsigned short* __restrict__ hTf32,
                                                float* __restrict__ s1_raw,
                                                float* __restrict__ s2_raw) {
    int tid = threadIdx.x;
    int lane = tid & 63;
    int c = lane & 15, g = lane >> 4;
    int r0 = blockIdx.x * 64 + (tid >> 6) * 16;
    f32x4 acc[16];
#pragma unroll
    for (int t = 0; t < 16; ++t) acc[t] = (f32x4){0.f, 0.f, 0.f, 0.f};
    const float* arow = input + (size_t)(r0 + c) * IN_FEAT;
#pragma unroll 1
    for (int kk = 0; kk < IN_FEAT / 32; ++kk) {
        int kb = kk * 32 + 8 * g;
        float4 x0 = *(const float4*)(arow + kb);
        float4 x1 = *(const float4*)(arow + kb + 4);
        u16x8v au;
        au[0] = f2bf(x0.x); au[1] = f2bf(x0.y); au[2] = f2bf(x0.z); au[3] = f2bf(x0.w);
        au[4] = f2bf(x1.x); au[5] = f2bf(x1.y); au[6] = f2bf(x1.z); au[7] = f2bf(x1.w);
        b16x8 af = __builtin_bit_cast(b16x8, au);
#pragma unroll
        for (int t = 0; t < 16; ++t) {
            b16x8 bf = __builtin_bit_cast(b16x8,
                *(const u16x8v*)(Wt + (size_t)(16 * t + c) * IN_FEAT + kb));
            acc[t] = __builtin_amdgcn_mfma_f32_16x16x32_bf16(af, bf, acc[t], 0, 0, 0);
        }
    }
    float a1v[16], a2v[16];
#pragma unroll
    for (int t = 0; t < 16; ++t) {
        a1v[t] = a_vec[16 * t + c];
        a2v[t] = a_vec[OUT_FEAT + 16 * t + c];
    }
#pragma unroll
    for (int r = 0; r < 4; ++r) {
        float s1p = 0.f, s2p = 0.f;
#pragma unroll
        for (int t = 0; t < 16; ++t) { s1p += acc[t][r] * a1v[t]; s2p += acc[t][r] * a2v[t]; }
#pragma unroll
        for (int m = 1; m <= 8; m <<= 1) { s1p += __shfl_xor(s1p, m); s2p += __shfl_xor(s2p, m); }
        if (c == 0) {
            int row = r0 + 4 * g + r;
            s1_raw[row] = s1p;
            s2_raw[row] = s2p;
        }
    }
    // store in 32x32 B-frag order
    int chunk16 = r0 >> 4;
    int lane_base = c + 32 * (g >> 1);
    int e0 = 4 * (g & 1);
#pragma unroll
    for (int t = 0; t < 16; ++t) {
        ushort4 pk;
        pk.x = f2bf(acc[t][0]); pk.y = f2bf(acc[t][1]);
        pk.z = f2bf(acc[t][2]); pk.w = f2bf(acc[t][3]);
        int lane_t = 16 * (t & 1) + lane_base;
        *(ushort4*)(hTf32 + ((size_t)(chunk16 * 8 + (t >> 1)) * 64 + lane_t) * 8 + e0) = pk;
    }
}

// K2: factored-exp constants.
__global__ __launch_bounds__(256) void k2_prep(const float* __restrict__ s1_raw,
                                               const float* __restrict__ s2_raw,
                                               float* __restrict__ e12,
                                               float2* __restrict__ row2) {
    __shared__ float red[256];
    int tid = threadIdx.x;
    float m = -3.0e38f;
    for (int j = tid; j < N_NODES; j += 256) m = fmaxf(m, s2_raw[j]);
    red[tid] = m;
    __syncthreads();
    for (int s = 128; s > 0; s >>= 1) {
        if (tid < s) red[tid] = fmaxf(red[tid], red[tid + s]);
        __syncthreads();
    }
    float M2 = red[0];
    int i = blockIdx.x * 256 + tid;
    float s1 = s1_raw[i];
    float u = s1 + M2;
    float mi = fmaxf(u, 0.2f * u);                 // per-row upper bound on e
    row2[i] = make_float2(__builtin_amdgcn_exp2f((s1 - mi) * LOG2E),
                          __builtin_amdgcn_exp2f((0.2f * s1 - mi) * LOG2E));
    float s2 = s2_raw[i];
    e12[2 * i]     = __builtin_amdgcn_exp2f(s2 * LOG2E);
    e12[2 * i + 1] = __builtin_amdgcn_exp2f(0.2f * s2 * LOG2E);
}

// K3 v16: 32x32-MFMA flash-GAT with af PRODUCE-ONCE / CONSUME-x4 sharing.
// Grid 1024 = 256 rowgroups (32 rows) x 4 jq. Block = 256 = 4 cq waves.
// af (the p-fragment) is identical across cq waves (same 32 rows) — so per
// group of 4 chunk16s, wave cq scores ONLY chunk grp*4+cq, writes af to
// laf[cq]; barrier; every wave consumes all 4 slots with its own 2 b-frags
// (2 MFMA each); barrier. ev-LDS reads and score VALU drop 4x.
// No HBM stream in flight at barriers (b-frags consumed within phase).
__global__ __launch_bounds__(256, 4) void k3_flash(const uint32_t* __restrict__ maskR,
                                                   const unsigned short* __restrict__ hTf32,
                                                   const float* __restrict__ e12g,
                                                   const float2* __restrict__ row2,
                                                   float* __restrict__ pout,
                                                   float* __restrict__ rowpart) {
    __shared__ __align__(16) float le12[4096];               // 16 KB
    __shared__ __align__(16) unsigned short laf[4][1024];    // 8 KB: af slots
    __shared__ float lsum[4][64];                            // 1 KB

    int tid = threadIdx.x;
    int cq = tid >> 6, lane = tid & 63;
    int lr = lane & 31, lo = lane >> 5;
    int jq = blockIdx.x & 3;
    int rg = blockIdx.x >> 2;
    int rowbase = rg * 32;

    // prologue: stage e12 quarter (16 floats/thread), one barrier
#pragma unroll
    for (int q = 0; q < 4; ++q) {
        *(float4*)&le12[tid * 16 + q * 4] =
            *(const float4*)(e12g + (size_t)jq * 4096 + tid * 16 + q * 4);
    }
    float2 rc = row2[rowbase + lr];
    float E1r = rc.x, E2r = rc.y;
    __syncthreads();

    // mask pointer: row lr, quarter jq (64 dwords), int4-grouped (8 chunk16s per int4)
    const int4* m4 = (const int4*)(maskR + (size_t)(rowbase + lr) * 256 + jq * 64);

    f32x16 acc0 = {0}, acc1 = {0};
    float lacc = 0.f;

#pragma unroll 1
    for (int kc8 = 0; kc8 < 16; ++kc8) {
        int4 mq = m4[kc8];           // masks for 8 chunk16s (4 dwords x 32 js)
        uint32_t md[4] = {(uint32_t)mq.x, (uint32_t)mq.y, (uint32_t)mq.z, (uint32_t)mq.w};
#pragma unroll
        for (int h = 0; h < 2; ++h) {
            int grp = kc8 * 2 + h;                    // group of 4 chunk16s
            int sl = h * 4 + cq;                      // produced slot within this int4
            int kc = kc8 * 8 + sl;                    // produced chunk16 (0..127)

            // ---- produce af for chunk kc ----
            float ev[16];
#pragma unroll
            for (int q = 0; q < 4; ++q)
                *(f32x4*)&ev[q * 4] = *(const f32x4*)&le12[(kc * 16 + 8 * lo) * 2 + q * 4];
            uint32_t mb = (md[sl >> 1] >> (16 * (sl & 1) + 8 * lo)) & 0xFFu;
            b16x8 af;
#pragma unroll
            for (int e = 0; e < 8; ++e) {
                float q0 = fmaxf(E1r * ev[2 * e], E2r * ev[2 * e + 1]);
                float p = (mb & (1u << e)) ? q0 : 0.f;
                lacc += p;
                af[e] = (__bf16)p;
            }
            *(u16x8v*)&laf[cq][lane * 8] = __builtin_bit_cast(u16x8v, af);
            __syncthreads();

            // ---- consume 4 slots with this wave's 2 col-tiles ----
            int gchunk0 = jq * 128 + grp * 4;
#pragma unroll
            for (int s = 0; s < 4; ++s) {
                const unsigned short* tb =
                    hTf32 + ((size_t)((gchunk0 + s) * 8 + 2 * cq) * 64 + lane) * 8;
                b16x8 bf0 = __builtin_bit_cast(b16x8, *(const u16x8v*)(tb));
                b16x8 bf1 = __builtin_bit_cast(b16x8, *(const u16x8v*)(tb + 512));
                b16x8 afs = __builtin_bit_cast(b16x8, *(const u16x8v*)&laf[s][lane * 8]);
                acc0 = __builtin_amdgcn_mfma_f32_32x32x16_bf16(afs, bf0, acc0, 0, 0, 0);
                acc1 = __builtin_amdgcn_mfma_f32_32x32x16_bf16(afs, bf1, acc1, 0, 0, 0);
            }
            __syncthreads();                          // before next group's overwrite
        }
    }

    // row sums: wave cq holds partials for chunks ≡ cq (mod 4); merge via LDS
    lsum[cq][lane] = lacc;
    __syncthreads();
    if (cq == 0) {
        float l = lsum[0][lane] + lsum[1][lane] + lsum[2][lane] + lsum[3][lane];
        float ltot = l + __shfl_xor(l, 32);
        if (lo == 0) rowpart[jq * N_NODES + rowbase + lr] = ltot;
    }

    // C layout (32x32): col = lane&31, row = (reg&3) + 8*(reg>>2) + 4*(lane>>5)
#pragma unroll
    for (int reg = 0; reg < 16; ++reg) {
        int row = (reg & 3) + 8 * (reg >> 2) + 4 * lo;
        size_t base = ((size_t)jq * N_NODES + rowbase + row) * OUT_FEAT + cq * 64 + lr;
        pout[base] = acc0[reg];
        pout[base + 32] = acc1[reg];
    }
}

// K4: out = elu( (sum_q pout[q]) / (sum_q rowpart[q]) ).
__global__ __launch_bounds__(256) void k4_reduce(const float* __restrict__ pout,
                                                 const float* __restrict__ rowpart,
                                                 float* __restrict__ out) {
    int t = blockIdx.x * 256 + threadIdx.x;
    int row = t >> 8;
    float s = 0.f, l = 0.f;
#pragma unroll
    for (int q = 0; q < 4; ++q) {
        s += pout[(size_t)q * N_NODES * OUT_FEAT + t];
        l += rowpart[q * N_NODES + row];
    }
    float inv = (l > 0.f) ? 1.0f / l : 0.f;
    float x = s * inv;
    out[t] = (x > 0.f) ? x : (__builtin_amdgcn_exp2f(x * LOG2E) - 1.0f);
}

extern "C" void kernel_launch(void* const* d_in, const int* in_sizes, int n_in,
                              void* d_out, int out_size, void* d_ws, size_t ws_size,
                              hipStream_t stream) {
    const float* input = (const float*)d_in[0];
    const int* adj = (const int*)d_in[1];
    const float* W = (const float*)d_in[2];
    const float* a_vec = (const float*)d_in[3];
    float* out = (float*)d_out;

    char* ws = (char*)d_ws;
    unsigned short* Wt    = (unsigned short*)(ws);               // 256 KB
    unsigned short* hTf32 = (unsigned short*)(ws + 262144);      // 4 MB
    float*  e12     = (float*)(ws + 4456448);                    // 64 KB
    float2* row2    = (float2*)(ws + 4521984);                   // 64 KB
    float*  s1_raw  = (float*)(ws + 4587520);                    // 32 KB
    float*  s2_raw  = (float*)(ws + 4620288);                    // 32 KB
    unsigned char* bitsR = (unsigned char*)(ws + 4653056);       // 8 MB
    float*  rowpart = (float*)(ws + 13041664);                   // 128 KB
    float*  pout    = (float*)(ws + 13172736);                   // 32 MB

    hipLaunchKernelGGL(k_pack, dim3(32768), dim3(256), 0, stream, adj, bitsR);
    hipLaunchKernelGGL(k0_transpose_w, dim3(512), dim3(256), 0, stream, W, Wt);
    hipLaunchKernelGGL(k1_hgemm, dim3(N_NODES / 64), dim3(256), 0, stream,
                       input, Wt, a_vec, hTf32, s1_raw, s2_raw);
    hipLaunchKernelGGL(k2_prep, dim3(32), dim3(256), 0, stream, s1_raw, s2_raw, e12, row2);
    hipLaunchKernelGGL(k3_flash, dim3(1024), dim3(256), 0, stream,
                       (const uint32_t*)bitsR, hTf32, e12, row2, pout, rowpart);
    hipLaunchKernelGGL(k4_reduce, dim3(N_NODES * OUT_FEAT / 256), dim3(256), 0, stream,
                       pout, rowpart, out);
}

// Round 18
// 157.759 us; speedup vs baseline: 1.3614x; 1.0207x over previous
//
#include <hip/hip_runtime.h>
#include <stdint.h>

#define N_NODES 8192
#define IN_FEAT 512
#define OUT_FEAT 256
#define LOG2E 1.4426950408889634f

typedef __bf16 b16x8 __attribute__((ext_vector_type(8)));
typedef unsigned short u16x8v __attribute__((ext_vector_type(8)));
typedef float f32x4 __attribute__((ext_vector_type(4)));
typedef float f32x16 __attribute__((ext_vector_type(16)));

static __device__ __forceinline__ unsigned short f2bf(float f) {
    union { float f; uint32_t u; } v; v.f = f;
    uint32_t r = v.u + 0x7FFFu + ((v.u >> 16) & 1u);
    return (unsigned short)(r >> 16);
}

// K_pack: adj int32 [8192][8192] -> ROW-MAJOR bitmask (8 MB). Fully coalesced
// (~45us @ 86% HBM). First 512 blocks also do the W transpose (folded k0).
__global__ __launch_bounds__(256) void k_pack(const int* __restrict__ adj,
                                              unsigned char* __restrict__ bitsR,
                                              const float* __restrict__ W,
                                              unsigned short* __restrict__ Wt) {
    size_t t = (size_t)blockIdx.x * 256 + threadIdx.x;
    const int4* a4 = (const int4*)adj + t * 2;
    int4 x0 = a4[0];
    int4 x1 = a4[1];
    unsigned b = (unsigned)(x0.x != 0)
               | ((unsigned)(x0.y != 0) << 1)
               | ((unsigned)(x0.z != 0) << 2)
               | ((unsigned)(x0.w != 0) << 3)
               | ((unsigned)(x1.x != 0) << 4)
               | ((unsigned)(x1.y != 0) << 5)
               | ((unsigned)(x1.z != 0) << 6)
               | ((unsigned)(x1.w != 0) << 7);
    bitsR[t] = (unsigned char)b;
    if (blockIdx.x < 512) {
        int t0 = blockIdx.x * 256 + threadIdx.x;     // 0..131071
        int c = t0 & (OUT_FEAT - 1);
        int k = t0 >> 8;
        Wt[(size_t)c * IN_FEAT + k] = f2bf(W[(size_t)k * OUT_FEAT + c]);
    }
}

// K1: h = X @ W via bf16 MFMA (16x16x32 internally). Writes hTf32 in the
// B-fragment order of mfma_f32_32x32x16_bf16 (verified R16).
__global__ __launch_bounds__(256) void k1_hgemm(const float* __restrict__ input,
                                                const unsigned short* __restrict__ Wt,
                                                const float* __restrict__ a_vec,
                                                unsigned short* __restrict__ hTf32,
                                                float* __restrict__ s1_raw,
                                                float* __restrict__ s2_raw) {
    int tid = threadIdx.x;
    int lane = tid & 63;
    int c = lane & 15, g = lane >> 4;
    int r0 = blockIdx.x * 64 + (tid >> 6) * 16;
    f32x4 acc[16];
#pragma unroll
    for (int t = 0; t < 16; ++t) acc[t] = (f32x4){0.f, 0.f, 0.f, 0.f};
    const float* arow = input + (size_t)(r0 + c) * IN_FEAT;
#pragma unroll 1
    for (int kk = 0; kk < IN_FEAT / 32; ++kk) {
        int kb = kk * 32 + 8 * g;
        float4 x0 = *(const float4*)(arow + kb);
        float4 x1 = *(const float4*)(arow + kb + 4);
        u16x8v au;
        au[0] = f2bf(x0.x); au[1] = f2bf(x0.y); au[2] = f2bf(x0.z); au[3] = f2bf(x0.w);
        au[4] = f2bf(x1.x); au[5] = f2bf(x1.y); au[6] = f2bf(x1.z); au[7] = f2bf(x1.w);
        b16x8 af = __builtin_bit_cast(b16x8, au);
#pragma unroll
        for (int t = 0; t < 16; ++t) {
            b16x8 bf = __builtin_bit_cast(b16x8,
                *(const u16x8v*)(Wt + (size_t)(16 * t + c) * IN_FEAT + kb));
            acc[t] = __builtin_amdgcn_mfma_f32_16x16x32_bf16(af, bf, acc[t], 0, 0, 0);
        }
    }
    float a1v[16], a2v[16];
#pragma unroll
    for (int t = 0; t < 16; ++t) {
        a1v[t] = a_vec[16 * t + c];
        a2v[t] = a_vec[OUT_FEAT + 16 * t + c];
    }
#pragma unroll
    for (int r = 0; r < 4; ++r) {
        float s1p = 0.f, s2p = 0.f;
#pragma unroll
        for (int t = 0; t < 16; ++t) { s1p += acc[t][r] * a1v[t]; s2p += acc[t][r] * a2v[t]; }
#pragma unroll
        for (int m = 1; m <= 8; m <<= 1) { s1p += __shfl_xor(s1p, m); s2p += __shfl_xor(s2p, m); }
        if (c == 0) {
            int row = r0 + 4 * g + r;
            s1_raw[row] = s1p;
            s2_raw[row] = s2p;
        }
    }
    // store in 32x32 B-frag order
    int chunk16 = r0 >> 4;
    int lane_base = c + 32 * (g >> 1);
    int e0 = 4 * (g & 1);
#pragma unroll
    for (int t = 0; t < 16; ++t) {
        ushort4 pk;
        pk.x = f2bf(acc[t][0]); pk.y = f2bf(acc[t][1]);
        pk.z = f2bf(acc[t][2]); pk.w = f2bf(acc[t][3]);
        int lane_t = 16 * (t & 1) + lane_base;
        *(ushort4*)(hTf32 + ((size_t)(chunk16 * 8 + (t >> 1)) * 64 + lane_t) * 8 + e0) = pk;
    }
}

// K2: factored-exp constants.
__global__ __launch_bounds__(256) void k2_prep(const float* __restrict__ s1_raw,
                                               const float* __restrict__ s2_raw,
                                               float* __restrict__ e12,
                                               float2* __restrict__ row2) {
    __shared__ float red[256];
    int tid = threadIdx.x;
    float m = -3.0e38f;
    for (int j = tid; j < N_NODES; j += 256) m = fmaxf(m, s2_raw[j]);
    red[tid] = m;
    __syncthreads();
    for (int s = 128; s > 0; s >>= 1) {
        if (tid < s) red[tid] = fmaxf(red[tid], red[tid + s]);
        __syncthreads();
    }
    float M2 = red[0];
    int i = blockIdx.x * 256 + tid;
    float s1 = s1_raw[i];
    float u = s1 + M2;
    float mi = fmaxf(u, 0.2f * u);                 // per-row upper bound on e
    row2[i] = make_float2(__builtin_amdgcn_exp2f((s1 - mi) * LOG2E),
                          __builtin_amdgcn_exp2f((0.2f * s1 - mi) * LOG2E));
    float s2 = s2_raw[i];
    e12[2 * i]     = __builtin_amdgcn_exp2f(s2 * LOG2E);
    e12[2 * i + 1] = __builtin_amdgcn_exp2f(0.2f * s2 * LOG2E);
}

// K3 v17: af sharing with 2-DEEP produce (barriers halved) + mask prefetch.
// Grid 1024 = 256 rowgroups (32 rows) x 4 jq. Block = 256 = 4 cq waves.
// Per int4-mask group (8 chunk16s): wave cq produces af for chunks 8k+cq and
// 8k+4+cq into laf slots cq / 4+cq; ONE barrier; all waves consume 8 slots
// (af ds_read + 2 distinct b-frags + 2 MFMA each); ONE barrier. Next group's
// mask int4 is issued at consume start (full phase of latency cover).
__global__ __launch_bounds__(256, 4) void k3_flash(const uint32_t* __restrict__ maskR,
                                                   const unsigned short* __restrict__ hTf32,
                                                   const float* __restrict__ e12g,
                                                   const float2* __restrict__ row2,
                                                   float* __restrict__ pout,
                                                   float* __restrict__ rowpart) {
    __shared__ __align__(16) float le12[4096];               // 16 KB
    __shared__ __align__(16) unsigned short laf[8][512];     // 8 KB: af slots
    __shared__ float lsum[4][64];                            // 1 KB

    int tid = threadIdx.x;
    int cq = tid >> 6, lane = tid & 63;
    int lr = lane & 31, lo = lane >> 5;
    int jq = blockIdx.x & 3;
    int rg = blockIdx.x >> 2;
    int rowbase = rg * 32;

    // prologue: stage e12 quarter (16 floats/thread), one barrier
#pragma unroll
    for (int q = 0; q < 4; ++q) {
        *(float4*)&le12[tid * 16 + q * 4] =
            *(const float4*)(e12g + (size_t)jq * 4096 + tid * 16 + q * 4);
    }
    float2 rc = row2[rowbase + lr];
    float E1r = rc.x, E2r = rc.y;
    __syncthreads();

    // mask pointer: row lr, quarter jq (64 dwords), int4-grouped (8 chunk16s per int4)
    const int4* m4 = (const int4*)(maskR + (size_t)(rowbase + lr) * 256 + jq * 64);

    f32x16 acc0 = {0}, acc1 = {0};
    float lacc = 0.f;
    int4 mq = m4[0];

#pragma unroll 1
    for (int kc8 = 0; kc8 < 16; ++kc8) {
        uint32_t md[4] = {(uint32_t)mq.x, (uint32_t)mq.y, (uint32_t)mq.z, (uint32_t)mq.w};

        // ---- produce 2 af slots (chunks kc8*8+cq, kc8*8+4+cq) ----
#pragma unroll
        for (int hh = 0; hh < 2; ++hh) {
            int sl = hh * 4 + cq;
            int kc = kc8 * 8 + sl;
            float ev[16];
#pragma unroll
            for (int q = 0; q < 4; ++q)
                *(f32x4*)&ev[q * 4] = *(const f32x4*)&le12[(kc * 16 + 8 * lo) * 2 + q * 4];
            uint32_t mb = (md[sl >> 1] >> (16 * (sl & 1) + 8 * lo)) & 0xFFu;
            b16x8 af;
#pragma unroll
            for (int e = 0; e < 8; ++e) {
                float q0 = fmaxf(E1r * ev[2 * e], E2r * ev[2 * e + 1]);
                float p = (mb & (1u << e)) ? q0 : 0.f;
                lacc += p;
                af[e] = (__bf16)p;
            }
            *(u16x8v*)&laf[sl][lane * 8] = __builtin_bit_cast(u16x8v, af);
        }
        __syncthreads();

        // prefetch next group's mask (consumed after the next barrier)
        if (kc8 < 15) mq = m4[kc8 + 1];

        // ---- consume 8 slots with this wave's 2 col-tiles ----
        int gchunk0 = jq * 128 + kc8 * 8;
#pragma unroll
        for (int s = 0; s < 8; ++s) {
            const unsigned short* tb =
                hTf32 + ((size_t)((gchunk0 + s) * 8 + 2 * cq) * 64 + lane) * 8;
            b16x8 bf0 = __builtin_bit_cast(b16x8, *(const u16x8v*)(tb));
            b16x8 bf1 = __builtin_bit_cast(b16x8, *(const u16x8v*)(tb + 512));
            b16x8 afs = __builtin_bit_cast(b16x8, *(const u16x8v*)&laf[s][lane * 8]);
            acc0 = __builtin_amdgcn_mfma_f32_32x32x16_bf16(afs, bf0, acc0, 0, 0, 0);
            acc1 = __builtin_amdgcn_mfma_f32_32x32x16_bf16(afs, bf1, acc1, 0, 0, 0);
        }
        __syncthreads();                          // before next group's laf overwrite
    }

    // row sums: wave cq produced chunks ≡ {cq, cq+4} (mod 8); merge via LDS
    lsum[cq][lane] = lacc;
    __syncthreads();
    if (cq == 0) {
        float l = lsum[0][lane] + lsum[1][lane] + lsum[2][lane] + lsum[3][lane];
        float ltot = l + __shfl_xor(l, 32);
        if (lo == 0) rowpart[jq * N_NODES + rowbase + lr] = ltot;
    }

    // C layout (32x32): col = lane&31, row = (reg&3) + 8*(reg>>2) + 4*(lane>>5)
#pragma unroll
    for (int reg = 0; reg < 16; ++reg) {
        int row = (reg & 3) + 8 * (reg >> 2) + 4 * lo;
        size_t base = ((size_t)jq * N_NODES + rowbase + row) * OUT_FEAT + cq * 64 + lr;
        pout[base] = acc0[reg];
        pout[base + 32] = acc1[reg];
    }
}

// K4: out = elu( (sum_q pout[q]) / (sum_q rowpart[q]) ).
__global__ __launch_bounds__(256) void k4_reduce(const float* __restrict__ pout,
                                                 const float* __restrict__ rowpart,
                                                 float* __restrict__ out) {
    int t = blockIdx.x * 256 + threadIdx.x;
    int row = t >> 8;
    float s = 0.f, l = 0.f;
#pragma unroll
    for (int q = 0; q < 4; ++q) {
        s += pout[(size_t)q * N_NODES * OUT_FEAT + t];
        l += rowpart[q * N_NODES + row];
    }
    float inv = (l > 0.f) ? 1.0f / l : 0.f;
    float x = s * inv;
    out[t] = (x > 0.f) ? x : (__builtin_amdgcn_exp2f(x * LOG2E) - 1.0f);
}

extern "C" void kernel_launch(void* const* d_in, const int* in_sizes, int n_in,
                              void* d_out, int out_size, void* d_ws, size_t ws_size,
                              hipStream_t stream) {
    const float* input = (const float*)d_in[0];
    const int* adj = (const int*)d_in[1];
    const float* W = (const float*)d_in[2];
    const float* a_vec = (const float*)d_in[3];
    float* out = (float*)d_out;

    char* ws = (char*)d_ws;
    unsigned short* Wt    = (unsigned short*)(ws);               // 256 KB
    unsigned short* hTf32 = (unsigned short*)(ws + 262144);      // 4 MB
    float*  e12     = (float*)(ws + 4456448);                    // 64 KB
    float2* row2    = (float2*)(ws + 4521984);                   // 64 KB
    float*  s1_raw  = (float*)(ws + 4587520);                    // 32 KB
    float*  s2_raw  = (float*)(ws + 4620288);                    // 32 KB
    unsigned char* bitsR = (unsigned char*)(ws + 4653056);       // 8 MB
    float*  rowpart = (float*)(ws + 13041664);                   // 128 KB
    float*  pout    = (float*)(ws + 13172736);                   // 32 MB

    hipLaunchKernelGGL(k_pack, dim3(32768), dim3(256), 0, stream, adj, bitsR, W, Wt);
    hipLaunchKernelGGL(k1_hgemm, dim3(N_NODES / 64), dim3(256), 0, stream,
                       input, Wt, a_vec, hTf32, s1_raw, s2_raw);
    hipLaunchKernelGGL(k2_prep, dim3(32), dim3(256), 0, stream, s1_raw, s2_raw, e12, row2);
    hipLaunchKernelGGL(k3_flash, dim3(1024), dim3(256), 0, stream,
                       (const uint32_t*)bitsR, hTf32, e12, row2, pout, rowpart);
    hipLaunchKernelGGL(k4_reduce, dim3(N_NODES * OUT_FEAT / 256), dim3(256), 0, stream,
                       pout, rowpart, out);
}